// Round 7
// baseline (1745.700 us; speedup 1.0000x reference)
//
#include <hip/hip_runtime.h>

// ---------- types / helpers ----------
typedef __bf16 bx8 __attribute__((ext_vector_type(8)));
typedef float fx4 __attribute__((ext_vector_type(4)));

#define GAS(p) ((const __attribute__((address_space(1))) void*)(const void*)(p))
#define LAS(p) ((__attribute__((address_space(3))) void*)(void*)(p))

__device__ __forceinline__ unsigned short f2bf(float f) {
  return __builtin_bit_cast(unsigned short, (__bf16)f);  // native RTNE
}
__device__ __forceinline__ float bf2f(unsigned short s) {
  unsigned u = ((unsigned)s) << 16;
  return __builtin_bit_cast(float, u);
}

// ---------- tiled weight transpose + bf16 cast: dst[l][n][k] = (bf16)src[l][k][n] ----------
__global__ __launch_bounds__(256) void wtrans_kernel(const float* __restrict__ src,
                                                     unsigned short* __restrict__ dst,
                                                     int K, int N) {
  __shared__ unsigned short t[64][68];
  const int l = blockIdx.z;
  const float* s = src + (size_t)l * K * N;
  unsigned short* d = dst + (size_t)l * N * K;
  const int n0 = blockIdx.x * 64, k0 = blockIdx.y * 64;
  const int tx = threadIdx.x & 63, ty = threadIdx.x >> 6;
#pragma unroll
  for (int r = 0; r < 64; r += 4)
    t[tx][ty + r] = f2bf(s[(size_t)(k0 + ty + r) * N + n0 + tx]);
  __syncthreads();
#pragma unroll
  for (int r = 0; r < 64; r += 4)
    d[(size_t)(n0 + ty + r) * K + k0 + tx] = t[ty + r][tx];
}

// ---------- embed: x + col_emb[t] + pos_emb[t+1] ----------
__global__ __launch_bounds__(256) void embed_kernel(const float4* __restrict__ x,
                                                    const float4* __restrict__ ce,
                                                    const float4* __restrict__ pe,
                                                    float4* __restrict__ o) {
  int i = blockIdx.x * 256 + threadIdx.x;
  int c4 = i & 63;
  int t = (i >> 6) & 255;
  float4 a = x[i], b = ce[t * 64 + c4], p = pe[(t + 1) * 64 + c4];
  o[i] = make_float4(a.x + b.x + p.x, a.y + b.y + p.y, a.z + b.z + p.z, a.w + b.w + p.w);
}

// ---------- LayerNorm ----------
template <int MODE>
__global__ __launch_bounds__(256) void ln_kernel(const float* __restrict__ x,
                                                 const float* __restrict__ gw,
                                                 const float* __restrict__ bw,
                                                 unsigned short* __restrict__ out,
                                                 float2* __restrict__ stats) {
  int row = blockIdx.x * 4 + (threadIdx.x >> 6);
  int lane = threadIdx.x & 63;
  const float4 v = *(const float4*)(x + (size_t)row * 256 + lane * 4);
  float s = v.x + v.y + v.z + v.w;
  float q = v.x * v.x + v.y * v.y + v.z * v.z + v.w * v.w;
#pragma unroll
  for (int off = 1; off < 64; off <<= 1) {
    s += __shfl_xor(s, off);
    q += __shfl_xor(q, off);
  }
  float mean = s * (1.0f / 256.0f);
  float rs = rsqrtf(q * (1.0f / 256.0f) - mean * mean + 1e-5f);
  if (MODE == 1) {
    if (lane == 0) stats[row] = make_float2(mean, rs);
    return;
  }
  float4 gv = *(const float4*)(gw + lane * 4);
  float4 bv = *(const float4*)(bw + lane * 4);
  ushort4 o;
  o.x = f2bf((v.x - mean) * rs * gv.x + bv.x);
  o.y = f2bf((v.y - mean) * rs * gv.y + bv.y);
  o.z = f2bf((v.z - mean) * rs * gv.z + bv.z);
  o.w = f2bf((v.w - mean) * rs * gv.w + bv.w);
  *(ushort4*)(out + (size_t)row * 256 + lane * 4) = o;
}

// ---------- final mean, two-stage ----------
__global__ __launch_bounds__(256) void mean_part_kernel(const float* __restrict__ x,
                                                        const float2* __restrict__ stats,
                                                        float* __restrict__ part) {
  int b = blockIdx.x, half = blockIdx.y, c = threadIdx.x;
  const float* xb = x + (size_t)b * 65536 + half * 32768;
  const float2* st = stats + b * 256 + half * 128;
  float acc = 0.f;
#pragma unroll 4
  for (int t = 0; t < 128; ++t) {
    float2 s = st[t];
    acc += (xb[t * 256 + c] - s.x) * s.y;
  }
  part[(size_t)(b * 2 + half) * 256 + c] = acc;
}
__global__ __launch_bounds__(256) void mean_fin_kernel(const float* __restrict__ part,
                                                       const float* __restrict__ fg,
                                                       const float* __restrict__ fb,
                                                       float* __restrict__ out) {
  int b = blockIdx.x, c = threadIdx.x;
  out[b * 256 + c] =
      (part[(size_t)(2 * b) * 256 + c] + part[(size_t)(2 * b + 1) * 256 + c]) *
          (1.0f / 256.0f) * fg[c] + fb[c];
}

// ---------- GEMM with OPERAND-SWAPPED MFMA (vectorized epilogue) ----------
// acc[i][j] = mfma(bq[j], af[i], ·): lane (g,lr) reg r holds
//   C[m0+wr*64+i*16+lr][n0+wc*64+j*16+4g+r]
// EP 1: out_bf16 = gelu_exact(acc + bvec)
// EP 2: resid += acc + bvec + col_bias[s][n]  (float4 RMW)
// EP 3: resid += acc + bvec                   (float4 RMW)
// EP 4: qkv: cols<512 -> outb; cols>=512 (V) -> vT in attn-Vl swizzled image
template <int EP>
__global__ __launch_bounds__(256) void gemm_kernel(const unsigned short* __restrict__ A,
                                                   const unsigned short* __restrict__ BT,
                                                   const float* __restrict__ bvec,
                                                   const float* __restrict__ cbias,
                                                   float* __restrict__ resid,
                                                   unsigned short* __restrict__ outb,
                                                   int N, int K) {
  __shared__ unsigned short lA[2][128 * 32];
  __shared__ unsigned short lB[2][128 * 32];
  const int tid = threadIdx.x;
  const int lane = tid & 63, w = tid >> 6;
  const int wr = w >> 1, wc = w & 1;
  const int g = lane >> 4, lr = lane & 15;
  const int m0 = blockIdx.y * 128, n0 = blockIdx.x * 128;
  fx4 acc[4][4] = {};

  auto STAGE = [&](int buf, int kk) {
#pragma unroll
    for (int r = 0; r < 2; ++r) {
      int u = r * 256 + tid;
      int row = u >> 2, sl = u & 3;
      int c = sl ^ ((row >> 1) & 3);
      __builtin_amdgcn_global_load_lds(GAS(A + (size_t)(m0 + row) * K + kk + c * 8),
                                       LAS(&lA[buf][u * 8]), 16, 0, 0);
      __builtin_amdgcn_global_load_lds(GAS(BT + (size_t)(n0 + row) * K + kk + c * 8),
                                       LAS(&lB[buf][u * 8]), 16, 0, 0);
    }
  };
  auto COMPUTE = [&](int buf) {
    bx8 af[4], bq[4];
#pragma unroll
    for (int i = 0; i < 4; ++i) {
      int row = wr * 64 + i * 16 + lr;
      af[i] = *(const bx8*)&lA[buf][row * 32 + (g ^ ((row >> 1) & 3)) * 8];
      int col = wc * 64 + i * 16 + lr;
      bq[i] = *(const bx8*)&lB[buf][col * 32 + (g ^ ((col >> 1) & 3)) * 8];
    }
#pragma unroll
    for (int i = 0; i < 4; ++i)
#pragma unroll
      for (int j = 0; j < 4; ++j)
        acc[i][j] = __builtin_amdgcn_mfma_f32_16x16x32_bf16(bq[j], af[i], acc[i][j], 0, 0, 0);
  };

  STAGE(0, 0);
  asm volatile("s_waitcnt vmcnt(0)" ::: "memory");
  __syncthreads();
  int cur = 0;
  const int nt = K >> 5;
  for (int t2 = 1; t2 < nt; ++t2) {
    STAGE(cur ^ 1, t2 * 32);
    COMPUTE(cur);
    __syncthreads();
    cur ^= 1;
  }
  COMPUTE(cur);

#pragma unroll
  for (int i = 0; i < 4; ++i) {
    const int m = m0 + wr * 64 + i * 16 + lr;
#pragma unroll
    for (int j = 0; j < 4; ++j) {
      const int nc = n0 + wc * 64 + j * 16 + g * 4;
      const float4 bv = *(const float4*)(bvec + nc);
      float v0 = acc[i][j][0] + bv.x, v1 = acc[i][j][1] + bv.y;
      float v2 = acc[i][j][2] + bv.z, v3 = acc[i][j][3] + bv.w;
      if constexpr (EP == 1) {
        v0 = 0.5f * v0 * (1.0f + erff(v0 * 0.70710678118654752f));
        v1 = 0.5f * v1 * (1.0f + erff(v1 * 0.70710678118654752f));
        v2 = 0.5f * v2 * (1.0f + erff(v2 * 0.70710678118654752f));
        v3 = 0.5f * v3 * (1.0f + erff(v3 * 0.70710678118654752f));
      }
      if constexpr (EP == 0 || EP == 1) {
        ushort4 st;
        st.x = f2bf(v0); st.y = f2bf(v1); st.z = f2bf(v2); st.w = f2bf(v3);
        *(ushort4*)(outb + (size_t)m * N + nc) = st;
      } else if constexpr (EP == 2 || EP == 3) {
        if constexpr (EP == 2) {
          const float4 cb = *(const float4*)(cbias + (size_t)(m & 255) * 256 + nc);
          v0 += cb.x; v1 += cb.y; v2 += cb.z; v3 += cb.w;
        }
        float4* rp = (float4*)(resid + (size_t)m * N + nc);
        float4 old = *rp;
        *rp = make_float4(old.x + v0, old.y + v1, old.z + v2, old.w + v3);
      } else {  // EP 4
        if (nc < 512) {
          ushort4 st;
          st.x = f2bf(v0); st.y = f2bf(v1); st.z = f2bf(v2); st.w = f2bf(v3);
          *(ushort4*)(outb + (size_t)m * N + nc) = st;
        } else {
          unsigned short* vTp = (unsigned short*)resid;
          const int s = m & 255, b = m >> 8;
          const int hv = nc - 512;
          const int h = hv >> 5, d0 = hv & 31;
          const int jj = (s & 3) + 4 * ((s >> 4) & 1);
          const int ub = (s >> 5) * 128 + ((s >> 2) & 3) * 32 + d0;
          unsigned short* base = vTp + (size_t)(b * 8 + h) * 8192;
          const float vv[4] = {v0, v1, v2, v3};
#pragma unroll
          for (int r = 0; r < 4; ++r) {
            int u = ub + r;
            int up = (u & ~7) | ((u & 7) ^ ((u >> 3) & 7));
            base[up * 8 + jj] = f2bf(vv[r]);
          }
        }
      }
    }
  }
}

// ---------- fused W2 + swiglu: g[m][n] = (u@W2a + b2a) * sigmoid(u@W2g + b2g) ----------
// Two B-tiles per block (a: w2T rows [n0,n0+128), gate: rows [256+n0, 256+n0+128)),
// two accumulator sets, 32 MFMA/K-step, K=1024. Writes g bf16 [M][256] directly.
__global__ __launch_bounds__(256) void gemm_w2f_kernel(const unsigned short* __restrict__ A,
                                                       const unsigned short* __restrict__ BT,
                                                       const float* __restrict__ b2,
                                                       unsigned short* __restrict__ gout) {
  __shared__ unsigned short lA[2][128 * 32];
  __shared__ unsigned short lBa[2][128 * 32];
  __shared__ unsigned short lBg[2][128 * 32];
  const int tid = threadIdx.x;
  const int lane = tid & 63, w = tid >> 6;
  const int wr = w >> 1, wc = w & 1;
  const int g = lane >> 4, lr = lane & 15;
  const int m0 = blockIdx.y * 128, n0 = blockIdx.x * 128;
  fx4 aA[4][4] = {}, aG[4][4] = {};

  auto STAGE = [&](int buf, int kk) {
#pragma unroll
    for (int r = 0; r < 2; ++r) {
      int u = r * 256 + tid;
      int row = u >> 2, sl = u & 3;
      int c = sl ^ ((row >> 1) & 3);
      __builtin_amdgcn_global_load_lds(GAS(A + (size_t)(m0 + row) * 1024 + kk + c * 8),
                                       LAS(&lA[buf][u * 8]), 16, 0, 0);
      __builtin_amdgcn_global_load_lds(GAS(BT + (size_t)(n0 + row) * 1024 + kk + c * 8),
                                       LAS(&lBa[buf][u * 8]), 16, 0, 0);
      __builtin_amdgcn_global_load_lds(GAS(BT + (size_t)(256 + n0 + row) * 1024 + kk + c * 8),
                                       LAS(&lBg[buf][u * 8]), 16, 0, 0);
    }
  };
  auto COMPUTE = [&](int buf) {
    bx8 af[4], ba[4], bg[4];
#pragma unroll
    for (int i = 0; i < 4; ++i) {
      int row = wr * 64 + i * 16 + lr;
      int sw = (g ^ ((row >> 1) & 3)) * 8;
      af[i] = *(const bx8*)&lA[buf][row * 32 + sw];
      int col = wc * 64 + i * 16 + lr;
      int swb = (g ^ ((col >> 1) & 3)) * 8;
      ba[i] = *(const bx8*)&lBa[buf][col * 32 + swb];
      bg[i] = *(const bx8*)&lBg[buf][col * 32 + swb];
    }
#pragma unroll
    for (int i = 0; i < 4; ++i)
#pragma unroll
      for (int j = 0; j < 4; ++j) {
        aA[i][j] = __builtin_amdgcn_mfma_f32_16x16x32_bf16(ba[j], af[i], aA[i][j], 0, 0, 0);
        aG[i][j] = __builtin_amdgcn_mfma_f32_16x16x32_bf16(bg[j], af[i], aG[i][j], 0, 0, 0);
      }
  };

  STAGE(0, 0);
  asm volatile("s_waitcnt vmcnt(0)" ::: "memory");
  __syncthreads();
  int cur = 0;
  for (int t2 = 1; t2 < 32; ++t2) {
    STAGE(cur ^ 1, t2 * 32);
    COMPUTE(cur);
    __syncthreads();
    cur ^= 1;
  }
  COMPUTE(cur);

#pragma unroll
  for (int i = 0; i < 4; ++i) {
    const int m = m0 + wr * 64 + i * 16 + lr;
#pragma unroll
    for (int j = 0; j < 4; ++j) {
      const int nc = n0 + wc * 64 + j * 16 + g * 4;
      const float4 bva = *(const float4*)(b2 + nc);
      const float4 bvg = *(const float4*)(b2 + 256 + nc);
      float a0 = aA[i][j][0] + bva.x, a1 = aA[i][j][1] + bva.y;
      float a2 = aA[i][j][2] + bva.z, a3 = aA[i][j][3] + bva.w;
      float g0 = aG[i][j][0] + bvg.x, g1 = aG[i][j][1] + bvg.y;
      float g2 = aG[i][j][2] + bvg.z, g3 = aG[i][j][3] + bvg.w;
      ushort4 st;
      st.x = f2bf(a0 / (1.0f + __expf(-g0)));
      st.y = f2bf(a1 / (1.0f + __expf(-g1)));
      st.z = f2bf(a2 / (1.0f + __expf(-g2)));
      st.w = f2bf(a3 / (1.0f + __expf(-g3)));
      *(ushort4*)(gout + (size_t)m * 256 + nc) = st;
    }
  }
}

// ---------- fused attention v3: V staged from pre-transposed vT ----------
// NOTE: NO min-waves launch-bounds arg — (256,4) capped VGPR at 64 and spilled.
__global__ __launch_bounds__(256) void attn_kernel(const unsigned short* __restrict__ qkv,
                                                   const unsigned short* __restrict__ vT,
                                                   const float* __restrict__ cbias,
                                                   unsigned short* __restrict__ attnb) {
  __shared__ unsigned short Kl[256 * 32];  // [s][d], 16B-unit swizzled
  __shared__ unsigned short Vl[1024 * 8];  // swizzled image, copied linearly from vT
  const int bh = blockIdx.x, b = bh >> 3, h = bh & 7;
  const int tid = threadIdx.x, lane = tid & 63, w = tid >> 6;
  const int g = lane >> 4, lr = lane & 15;
  const unsigned short* qb_ = qkv + (size_t)b * 196608;
  const unsigned short* vTb = vT + (size_t)bh * 8192;
#pragma unroll
  for (int r = 0; r < 4; ++r) {
    int u = r * 256 + tid;
    int s = u >> 2, sl = u & 3;
    int c = sl ^ ((s >> 1) & 3);
    __builtin_amdgcn_global_load_lds(GAS(qb_ + (size_t)s * 768 + 256 + h * 32 + c * 8),
                                     LAS(&Kl[u * 8]), 16, 0, 0);
    __builtin_amdgcn_global_load_lds(GAS(vTb + u * 8), LAS(&Vl[u * 8]), 16, 0, 0);
  }
  asm volatile("s_waitcnt vmcnt(0)" ::: "memory");
  __syncthreads();
  const float scale = 0.17677669529663689f;
  const fx4 zero = {0.f, 0.f, 0.f, 0.f};
#pragma unroll 1
  for (int it = 0; it < 4; ++it) {
    const int t = it * 64 + w * 16 + lr;
    bx8 qf = *(const bx8*)(qb_ + (size_t)t * 768 + h * 32 + g * 8);
    float p[16][4];
    float mx = -1e30f;
#pragma unroll
    for (int n = 0; n < 16; ++n) {
      int sr = n * 16 + lr;
      bx8 kf = *(const bx8*)&Kl[sr * 32 + (g ^ ((sr >> 1) & 3)) * 8];
      fx4 sc = __builtin_amdgcn_mfma_f32_16x16x32_bf16(kf, qf, zero, 0, 0, 0);
      const float4 cb = *(const float4*)(cbias + (size_t)t * 256 + n * 16 + g * 4);
      p[n][0] = sc[0] * scale + cb.x;
      p[n][1] = sc[1] * scale + cb.y;
      p[n][2] = sc[2] * scale + cb.z;
      p[n][3] = sc[3] * scale + cb.w;
      mx = fmaxf(mx, fmaxf(fmaxf(p[n][0], p[n][1]), fmaxf(p[n][2], p[n][3])));
    }
    mx = fmaxf(mx, __shfl_xor(mx, 16));
    mx = fmaxf(mx, __shfl_xor(mx, 32));
    float sum = 0.f;
    bx8 bq[8];
#pragma unroll
    for (int c = 0; c < 8; ++c) {
      union { bx8 v; unsigned short u[8]; } pk;
#pragma unroll
      for (int jj = 0; jj < 8; ++jj) {
        float e = __expf(p[2 * c + (jj >> 2)][jj & 3] - mx);
        sum += e;
        pk.u[jj] = f2bf(e);
      }
      bq[c] = pk.v;
    }
    sum += __shfl_xor(sum, 16);
    sum += __shfl_xor(sum, 32);
    const float inv = 1.0f / sum;
    fx4 oa0 = zero, oa1 = zero;
#pragma unroll
    for (int c = 0; c < 8; ++c) {
      int u0 = c * 128 + g * 32 + lr;
      int u0p = (u0 & ~7) | ((u0 & 7) ^ ((u0 >> 3) & 7));
      bx8 vf0 = *(const bx8*)&Vl[u0p * 8];
      oa0 = __builtin_amdgcn_mfma_f32_16x16x32_bf16(vf0, bq[c], oa0, 0, 0, 0);
      int u1 = u0 + 16;
      int u1p = (u1 & ~7) | ((u1 & 7) ^ ((u1 >> 3) & 7));
      bx8 vf1 = *(const bx8*)&Vl[u1p * 8];
      oa1 = __builtin_amdgcn_mfma_f32_16x16x32_bf16(vf1, bq[c], oa1, 0, 0, 0);
    }
    ushort4 o0, o1;
    o0.x = f2bf(oa0[0] * inv); o0.y = f2bf(oa0[1] * inv);
    o0.z = f2bf(oa0[2] * inv); o0.w = f2bf(oa0[3] * inv);
    o1.x = f2bf(oa1[0] * inv); o1.y = f2bf(oa1[1] * inv);
    o1.z = f2bf(oa1[2] * inv); o1.w = f2bf(oa1[3] * inv);
    unsigned short* orow = attnb + (size_t)(b * 256 + t) * 256 + h * 32;
    *(ushort4*)(orow + 4 * g) = o0;
    *(ushort4*)(orow + 16 + 4 * g) = o1;
  }
}

// ---------- orchestration ----------
extern "C" void kernel_launch(void* const* d_in, const int* in_sizes, int n_in,
                              void* d_out, int out_size, void* d_ws, size_t ws_size,
                              hipStream_t stream) {
  (void)in_sizes; (void)n_in; (void)out_size; (void)ws_size;
  const float* x     = (const float*)d_in[0];
  const float* cemb  = (const float*)d_in[1];
  const float* pemb  = (const float*)d_in[2];
  const float* cbias = (const float*)d_in[3];
  const float* ln1g  = (const float*)d_in[4];
  const float* ln1b  = (const float*)d_in[5];
  const float* qkvw  = (const float*)d_in[6];
  const float* qkvb  = (const float*)d_in[7];
  const float* outw  = (const float*)d_in[8];
  const float* outbv = (const float*)d_in[9];
  const float* ln2g  = (const float*)d_in[10];
  const float* ln2b  = (const float*)d_in[11];
  const float* w1    = (const float*)d_in[12];
  const float* b1    = (const float*)d_in[13];
  const float* w2    = (const float*)d_in[14];
  const float* b2    = (const float*)d_in[15];
  const float* w3    = (const float*)d_in[16];
  const float* b3    = (const float*)d_in[17];
  const float* fing  = (const float*)d_in[18];
  const float* finb  = (const float*)d_in[19];

  char* ws = (char*)d_ws;
  // Workspace layout (125.0 MB), bytes:
  //  R0 x_res fp32            [0,          33554432)
  //  R1 hn bf16 multiplex     [33554432,   50331648)  ln1-out -> attnb -> ln2-out -> g(W2f out)
  //  R2 big bf16              [50331648,  117440512)
  //     attn phase: qkv [50331648,100663296) + vT [100663296,117440512)
  //     MLP phase : u   [50331648,117440512)  (64 MB, overwrites qkv+vT)
  //  R3 wT bf16               [117440512, 130809856)
  //  R4 stats float2          [130809856, 131072000)
  float* x_res = (float*)(ws);
  unsigned short* hn   = (unsigned short*)(ws + 33554432);
  unsigned short* big  = (unsigned short*)(ws + 50331648);
  unsigned short* vT   = (unsigned short*)(ws + 100663296);
  unsigned short* wT   = (unsigned short*)(ws + 117440512);
  float2* stats = (float2*)(ws + 130809856);
  float* part  = (float*)big;  // mean partials: big dead by then

  unsigned short* qkvwT = wT;                 // 6*768*256
  unsigned short* outwT = wT + 1179648;       // 6*256*256
  unsigned short* w1T   = wT + 1572864;       // 6*1024*256
  unsigned short* w2T   = wT + 3145728;       // 6*512*1024
  unsigned short* w3T   = wT + 6291456;       // 6*256*256

  wtrans_kernel<<<dim3(12, 4, 6), 256, 0, stream>>>(qkvw, qkvwT, 256, 768);
  wtrans_kernel<<<dim3(4, 4, 6), 256, 0, stream>>>(outw, outwT, 256, 256);
  wtrans_kernel<<<dim3(16, 4, 6), 256, 0, stream>>>(w1, w1T, 256, 1024);
  wtrans_kernel<<<dim3(8, 16, 6), 256, 0, stream>>>(w2, w2T, 1024, 512);
  wtrans_kernel<<<dim3(4, 4, 6), 256, 0, stream>>>(w3, w3T, 256, 256);
  embed_kernel<<<8192, 256, 0, stream>>>((const float4*)x, (const float4*)cemb,
                                         (const float4*)pemb, (float4*)x_res);
  for (int l = 0; l < 6; ++l) {
    ln_kernel<0><<<8192, 256, 0, stream>>>(x_res, ln1g + l * 256, ln1b + l * 256, hn, nullptr);
    gemm_kernel<4><<<dim3(6, 256), 256, 0, stream>>>(hn, qkvwT + (size_t)l * 196608,
                                                     qkvb + l * 768, nullptr, (float*)vT,
                                                     big, 768, 256);
    attn_kernel<<<1024, 256, 0, stream>>>(big, vT, cbias, hn);
    gemm_kernel<2><<<dim3(2, 256), 256, 0, stream>>>(hn, outwT + (size_t)l * 65536,
                                                     outbv + l * 256, cbias, x_res, nullptr,
                                                     256, 256);
    ln_kernel<0><<<8192, 256, 0, stream>>>(x_res, ln2g + l * 256, ln2b + l * 256, hn, nullptr);
    // MLP, unchunked: u = gelu(hn@W1+b1) [32768x1024] into big (qkv+vT dead)
    gemm_kernel<1><<<dim3(8, 256), 256, 0, stream>>>(hn, w1T + (size_t)l * 262144,
                                                     b1 + l * 1024, nullptr, nullptr, big,
                                                     1024, 256);
    // g = (u@W2a+b2a)*sigmoid(u@W2g+b2g) -> hn (ln2-out dead after W1)
    gemm_w2f_kernel<<<dim3(2, 256), 256, 0, stream>>>(big, w2T + (size_t)l * 524288,
                                                      b2 + l * 512, hn);
    gemm_kernel<3><<<dim3(2, 256), 256, 0, stream>>>(hn, w3T + (size_t)l * 65536,
                                                     b3 + l * 256, nullptr, x_res, nullptr,
                                                     256, 256);
  }
  ln_kernel<1><<<8192, 256, 0, stream>>>(x_res, nullptr, nullptr, nullptr, stats);
  mean_part_kernel<<<dim3(128, 2), 256, 0, stream>>>(x_res, stats, part);
  mean_fin_kernel<<<128, 256, 0, stream>>>(part, fing, finb, (float*)d_out);
}

// Round 8
// 1571.417 us; speedup vs baseline: 1.1109x; 1.1109x over previous
//
#include <hip/hip_runtime.h>

// ---------- types / helpers ----------
typedef __bf16 bx8 __attribute__((ext_vector_type(8)));
typedef float fx4 __attribute__((ext_vector_type(4)));

#define GAS(p) ((const __attribute__((address_space(1))) void*)(const void*)(p))
#define LAS(p) ((__attribute__((address_space(3))) void*)(void*)(p))

__device__ __forceinline__ unsigned short f2bf(float f) {
  return __builtin_bit_cast(unsigned short, (__bf16)f);  // native RTNE
}
__device__ __forceinline__ float bf2f(unsigned short s) {
  unsigned u = ((unsigned)s) << 16;
  return __builtin_bit_cast(float, u);
}

// ---------- tiled weight transpose + bf16 cast: dst[l][n][k] = (bf16)src[l][k][n] ----------
__global__ __launch_bounds__(256) void wtrans_kernel(const float* __restrict__ src,
                                                     unsigned short* __restrict__ dst,
                                                     int K, int N) {
  __shared__ unsigned short t[64][68];
  const int l = blockIdx.z;
  const float* s = src + (size_t)l * K * N;
  unsigned short* d = dst + (size_t)l * N * K;
  const int n0 = blockIdx.x * 64, k0 = blockIdx.y * 64;
  const int tx = threadIdx.x & 63, ty = threadIdx.x >> 6;
#pragma unroll
  for (int r = 0; r < 64; r += 4)
    t[tx][ty + r] = f2bf(s[(size_t)(k0 + ty + r) * N + n0 + tx]);
  __syncthreads();
#pragma unroll
  for (int r = 0; r < 64; r += 4)
    d[(size_t)(n0 + ty + r) * K + k0 + tx] = t[ty + r][tx];
}

// ---------- embed: x + col_emb[t] + pos_emb[t+1] ----------
__global__ __launch_bounds__(256) void embed_kernel(const float4* __restrict__ x,
                                                    const float4* __restrict__ ce,
                                                    const float4* __restrict__ pe,
                                                    float4* __restrict__ o) {
  int i = blockIdx.x * 256 + threadIdx.x;
  int c4 = i & 63;
  int t = (i >> 6) & 255;
  float4 a = x[i], b = ce[t * 64 + c4], p = pe[(t + 1) * 64 + c4];
  o[i] = make_float4(a.x + b.x + p.x, a.y + b.y + p.y, a.z + b.z + p.z, a.w + b.w + p.w);
}

// ---------- LayerNorm ----------
template <int MODE>
__global__ __launch_bounds__(256) void ln_kernel(const float* __restrict__ x,
                                                 const float* __restrict__ gw,
                                                 const float* __restrict__ bw,
                                                 unsigned short* __restrict__ out,
                                                 float2* __restrict__ stats) {
  int row = blockIdx.x * 4 + (threadIdx.x >> 6);
  int lane = threadIdx.x & 63;
  const float4 v = *(const float4*)(x + (size_t)row * 256 + lane * 4);
  float s = v.x + v.y + v.z + v.w;
  float q = v.x * v.x + v.y * v.y + v.z * v.z + v.w * v.w;
#pragma unroll
  for (int off = 1; off < 64; off <<= 1) {
    s += __shfl_xor(s, off);
    q += __shfl_xor(q, off);
  }
  float mean = s * (1.0f / 256.0f);
  float rs = rsqrtf(q * (1.0f / 256.0f) - mean * mean + 1e-5f);
  if (MODE == 1) {
    if (lane == 0) stats[row] = make_float2(mean, rs);
    return;
  }
  float4 gv = *(const float4*)(gw + lane * 4);
  float4 bv = *(const float4*)(bw + lane * 4);
  ushort4 o;
  o.x = f2bf((v.x - mean) * rs * gv.x + bv.x);
  o.y = f2bf((v.y - mean) * rs * gv.y + bv.y);
  o.z = f2bf((v.z - mean) * rs * gv.z + bv.z);
  o.w = f2bf((v.w - mean) * rs * gv.w + bv.w);
  *(ushort4*)(out + (size_t)row * 256 + lane * 4) = o;
}

// ---------- final mean, two-stage ----------
__global__ __launch_bounds__(256) void mean_part_kernel(const float* __restrict__ x,
                                                        const float2* __restrict__ stats,
                                                        float* __restrict__ part) {
  int b = blockIdx.x, half = blockIdx.y, c = threadIdx.x;
  const float* xb = x + (size_t)b * 65536 + half * 32768;
  const float2* st = stats + b * 256 + half * 128;
  float acc = 0.f;
#pragma unroll 4
  for (int t = 0; t < 128; ++t) {
    float2 s = st[t];
    acc += (xb[t * 256 + c] - s.x) * s.y;
  }
  part[(size_t)(b * 2 + half) * 256 + c] = acc;
}
__global__ __launch_bounds__(256) void mean_fin_kernel(const float* __restrict__ part,
                                                       const float* __restrict__ fg,
                                                       const float* __restrict__ fb,
                                                       float* __restrict__ out) {
  int b = blockIdx.x, c = threadIdx.x;
  out[b * 256 + c] =
      (part[(size_t)(2 * b) * 256 + c] + part[(size_t)(2 * b + 1) * 256 + c]) *
          (1.0f / 256.0f) * fg[c] + fb[c];
}

// ---------- GEMM 128x128 (operand-swapped MFMA, vectorized epilogue) ----------
// acc[i][j] = mfma(bq[j], af[i], ·): lane (g,lr) reg r holds
//   C[m0+wr*64+i*16+lr][n0+wc*64+j*16+4g+r]
// EP 1: out_bf16 = gelu_exact(acc + bvec)
// EP 4: qkv: cols<512 -> outb; cols>=512 (V) -> vT in attn-Vl swizzled image
template <int EP>
__global__ __launch_bounds__(256) void gemm_kernel(const unsigned short* __restrict__ A,
                                                   const unsigned short* __restrict__ BT,
                                                   const float* __restrict__ bvec,
                                                   const float* __restrict__ cbias,
                                                   float* __restrict__ resid,
                                                   unsigned short* __restrict__ outb,
                                                   int N, int K) {
  __shared__ unsigned short lA[2][128 * 32];
  __shared__ unsigned short lB[2][128 * 32];
  const int tid = threadIdx.x;
  const int lane = tid & 63, w = tid >> 6;
  const int wr = w >> 1, wc = w & 1;
  const int g = lane >> 4, lr = lane & 15;
  const int m0 = blockIdx.y * 128, n0 = blockIdx.x * 128;
  fx4 acc[4][4] = {};

  auto STAGE = [&](int buf, int kk) {
#pragma unroll
    for (int r = 0; r < 2; ++r) {
      int u = r * 256 + tid;
      int row = u >> 2, sl = u & 3;
      int c = sl ^ ((row >> 1) & 3);
      __builtin_amdgcn_global_load_lds(GAS(A + (size_t)(m0 + row) * K + kk + c * 8),
                                       LAS(&lA[buf][u * 8]), 16, 0, 0);
      __builtin_amdgcn_global_load_lds(GAS(BT + (size_t)(n0 + row) * K + kk + c * 8),
                                       LAS(&lB[buf][u * 8]), 16, 0, 0);
    }
  };
  auto COMPUTE = [&](int buf) {
    bx8 af[4], bq[4];
#pragma unroll
    for (int i = 0; i < 4; ++i) {
      int row = wr * 64 + i * 16 + lr;
      af[i] = *(const bx8*)&lA[buf][row * 32 + (g ^ ((row >> 1) & 3)) * 8];
      int col = wc * 64 + i * 16 + lr;
      bq[i] = *(const bx8*)&lB[buf][col * 32 + (g ^ ((col >> 1) & 3)) * 8];
    }
#pragma unroll
    for (int i = 0; i < 4; ++i)
#pragma unroll
      for (int j = 0; j < 4; ++j)
        acc[i][j] = __builtin_amdgcn_mfma_f32_16x16x32_bf16(bq[j], af[i], acc[i][j], 0, 0, 0);
  };

  STAGE(0, 0);
  asm volatile("s_waitcnt vmcnt(0)" ::: "memory");
  __syncthreads();
  int cur = 0;
  const int nt = K >> 5;
  for (int t2 = 1; t2 < nt; ++t2) {
    STAGE(cur ^ 1, t2 * 32);
    COMPUTE(cur);
    __syncthreads();
    cur ^= 1;
  }
  COMPUTE(cur);

#pragma unroll
  for (int i = 0; i < 4; ++i) {
    const int m = m0 + wr * 64 + i * 16 + lr;
#pragma unroll
    for (int j = 0; j < 4; ++j) {
      const int nc = n0 + wc * 64 + j * 16 + g * 4;
      const float4 bv = *(const float4*)(bvec + nc);
      float v0 = acc[i][j][0] + bv.x, v1 = acc[i][j][1] + bv.y;
      float v2 = acc[i][j][2] + bv.z, v3 = acc[i][j][3] + bv.w;
      if constexpr (EP == 1) {
        v0 = 0.5f * v0 * (1.0f + erff(v0 * 0.70710678118654752f));
        v1 = 0.5f * v1 * (1.0f + erff(v1 * 0.70710678118654752f));
        v2 = 0.5f * v2 * (1.0f + erff(v2 * 0.70710678118654752f));
        v3 = 0.5f * v3 * (1.0f + erff(v3 * 0.70710678118654752f));
      }
      if constexpr (EP == 0 || EP == 1) {
        ushort4 st;
        st.x = f2bf(v0); st.y = f2bf(v1); st.z = f2bf(v2); st.w = f2bf(v3);
        *(ushort4*)(outb + (size_t)m * N + nc) = st;
      } else {  // EP 4
        if (nc < 512) {
          ushort4 st;
          st.x = f2bf(v0); st.y = f2bf(v1); st.z = f2bf(v2); st.w = f2bf(v3);
          *(ushort4*)(outb + (size_t)m * N + nc) = st;
        } else {
          unsigned short* vTp = (unsigned short*)resid;
          const int s = m & 255, b = m >> 8;
          const int hv = nc - 512;
          const int h = hv >> 5, d0 = hv & 31;
          const int jj = (s & 3) + 4 * ((s >> 4) & 1);
          const int ub = (s >> 5) * 128 + ((s >> 2) & 3) * 32 + d0;
          unsigned short* base = vTp + (size_t)(b * 8 + h) * 8192;
          const float vv[4] = {v0, v1, v2, v3};
#pragma unroll
          for (int r = 0; r < 4; ++r) {
            int u = ub + r;
            int up = (u & ~7) | ((u & 7) ^ ((u >> 3) & 7));
            base[up * 8 + jj] = f2bf(vv[r]);
          }
        }
      }
    }
  }
}

// ---------- GEMM 64x128 (BM=64) for skinny N=256 GEMMs: 4 blocks/CU ----------
// 4 waves, wave w covers cols [n0+w*32, +32): acc[i<4][j<2], lane reg r holds
//   C[m0+i*16+lr][n0+w*32+j*16+4g+r]
// EP 2: resid += acc + bvec + col_bias[s][n]  (float4 RMW)
// EP 3: resid += acc + bvec                   (float4 RMW)
template <int EP>
__global__ __launch_bounds__(256) void gemm64_kernel(const unsigned short* __restrict__ A,
                                                     const unsigned short* __restrict__ BT,
                                                     const float* __restrict__ bvec,
                                                     const float* __restrict__ cbias,
                                                     float* __restrict__ resid,
                                                     int N, int K) {
  __shared__ unsigned short lA[2][64 * 32];
  __shared__ unsigned short lB[2][128 * 32];
  const int tid = threadIdx.x;
  const int lane = tid & 63, w = tid >> 6;
  const int g = lane >> 4, lr = lane & 15;
  const int m0 = blockIdx.y * 64, n0 = blockIdx.x * 128;
  fx4 acc[4][2] = {};

  auto STAGE = [&](int buf, int kk) {
    {
      int u = tid;
      int row = u >> 2, sl = u & 3;
      int c = sl ^ ((row >> 1) & 3);
      __builtin_amdgcn_global_load_lds(GAS(A + (size_t)(m0 + row) * K + kk + c * 8),
                                       LAS(&lA[buf][u * 8]), 16, 0, 0);
    }
#pragma unroll
    for (int r = 0; r < 2; ++r) {
      int u = r * 256 + tid;
      int row = u >> 2, sl = u & 3;
      int c = sl ^ ((row >> 1) & 3);
      __builtin_amdgcn_global_load_lds(GAS(BT + (size_t)(n0 + row) * K + kk + c * 8),
                                       LAS(&lB[buf][u * 8]), 16, 0, 0);
    }
  };
  auto COMPUTE = [&](int buf) {
    bx8 af[4], bq[2];
#pragma unroll
    for (int i = 0; i < 4; ++i) {
      int row = i * 16 + lr;
      af[i] = *(const bx8*)&lA[buf][row * 32 + (g ^ ((row >> 1) & 3)) * 8];
    }
#pragma unroll
    for (int j = 0; j < 2; ++j) {
      int col = w * 32 + j * 16 + lr;
      bq[j] = *(const bx8*)&lB[buf][col * 32 + (g ^ ((col >> 1) & 3)) * 8];
    }
#pragma unroll
    for (int i = 0; i < 4; ++i)
#pragma unroll
      for (int j = 0; j < 2; ++j)
        acc[i][j] = __builtin_amdgcn_mfma_f32_16x16x32_bf16(bq[j], af[i], acc[i][j], 0, 0, 0);
  };

  STAGE(0, 0);
  asm volatile("s_waitcnt vmcnt(0)" ::: "memory");
  __syncthreads();
  int cur = 0;
  const int nt = K >> 5;
  for (int t2 = 1; t2 < nt; ++t2) {
    STAGE(cur ^ 1, t2 * 32);
    COMPUTE(cur);
    __syncthreads();
    cur ^= 1;
  }
  COMPUTE(cur);

#pragma unroll
  for (int i = 0; i < 4; ++i) {
    const int m = m0 + i * 16 + lr;
#pragma unroll
    for (int j = 0; j < 2; ++j) {
      const int nc = n0 + w * 32 + j * 16 + g * 4;
      const float4 bv = *(const float4*)(bvec + nc);
      float v0 = acc[i][j][0] + bv.x, v1 = acc[i][j][1] + bv.y;
      float v2 = acc[i][j][2] + bv.z, v3 = acc[i][j][3] + bv.w;
      if constexpr (EP == 2) {
        const float4 cb = *(const float4*)(cbias + (size_t)(m & 255) * 256 + nc);
        v0 += cb.x; v1 += cb.y; v2 += cb.z; v3 += cb.w;
      }
      float4* rp = (float4*)(resid + (size_t)m * N + nc);
      float4 old = *rp;
      *rp = make_float4(old.x + v0, old.y + v1, old.z + v2, old.w + v3);
    }
  }
}

// ---------- fused W2+swiglu, BM=64: g[m][nc] = (u@W2a+b2a)*sigmoid(u@W2g+b2g) ----------
// Wave w covers cols [n0+w*32,+32) of BOTH a and gate -> direct swiglu epilogue.
// LDS 40KB (A 8 + Ba 16 + Bg 16) -> 4 blocks/CU exact; grid (2,512) = 1024 blocks.
__global__ __launch_bounds__(256) void gemm_w2f64_kernel(const unsigned short* __restrict__ A,
                                                         const unsigned short* __restrict__ BT,
                                                         const float* __restrict__ b2,
                                                         unsigned short* __restrict__ gout) {
  __shared__ unsigned short lA[2][64 * 32];
  __shared__ unsigned short lBa[2][128 * 32];
  __shared__ unsigned short lBg[2][128 * 32];
  const int tid = threadIdx.x;
  const int lane = tid & 63, w = tid >> 6;
  const int g = lane >> 4, lr = lane & 15;
  const int m0 = blockIdx.y * 64, n0 = blockIdx.x * 128;
  fx4 aA[4][2] = {}, aG[4][2] = {};

  auto STAGE = [&](int buf, int kk) {
    {
      int u = tid;
      int row = u >> 2, sl = u & 3;
      int c = sl ^ ((row >> 1) & 3);
      __builtin_amdgcn_global_load_lds(GAS(A + (size_t)(m0 + row) * 1024 + kk + c * 8),
                                       LAS(&lA[buf][u * 8]), 16, 0, 0);
    }
#pragma unroll
    for (int r = 0; r < 2; ++r) {
      int u = r * 256 + tid;
      int row = u >> 2, sl = u & 3;
      int c = sl ^ ((row >> 1) & 3);
      __builtin_amdgcn_global_load_lds(GAS(BT + (size_t)(n0 + row) * 1024 + kk + c * 8),
                                       LAS(&lBa[buf][u * 8]), 16, 0, 0);
      __builtin_amdgcn_global_load_lds(GAS(BT + (size_t)(256 + n0 + row) * 1024 + kk + c * 8),
                                       LAS(&lBg[buf][u * 8]), 16, 0, 0);
    }
  };
  auto COMPUTE = [&](int buf) {
    bx8 af[4], ba[2], bg[2];
#pragma unroll
    for (int i = 0; i < 4; ++i) {
      int row = i * 16 + lr;
      af[i] = *(const bx8*)&lA[buf][row * 32 + (g ^ ((row >> 1) & 3)) * 8];
    }
#pragma unroll
    for (int j = 0; j < 2; ++j) {
      int col = w * 32 + j * 16 + lr;
      int sw = (g ^ ((col >> 1) & 3)) * 8;
      ba[j] = *(const bx8*)&lBa[buf][col * 32 + sw];
      bg[j] = *(const bx8*)&lBg[buf][col * 32 + sw];
    }
#pragma unroll
    for (int i = 0; i < 4; ++i)
#pragma unroll
      for (int j = 0; j < 2; ++j) {
        aA[i][j] = __builtin_amdgcn_mfma_f32_16x16x32_bf16(ba[j], af[i], aA[i][j], 0, 0, 0);
        aG[i][j] = __builtin_amdgcn_mfma_f32_16x16x32_bf16(bg[j], af[i], aG[i][j], 0, 0, 0);
      }
  };

  STAGE(0, 0);
  asm volatile("s_waitcnt vmcnt(0)" ::: "memory");
  __syncthreads();
  int cur = 0;
  for (int t2 = 1; t2 < 32; ++t2) {
    STAGE(cur ^ 1, t2 * 32);
    COMPUTE(cur);
    __syncthreads();
    cur ^= 1;
  }
  COMPUTE(cur);

#pragma unroll
  for (int i = 0; i < 4; ++i) {
    const int m = m0 + i * 16 + lr;
#pragma unroll
    for (int j = 0; j < 2; ++j) {
      const int nc = n0 + w * 32 + j * 16 + g * 4;
      const float4 bva = *(const float4*)(b2 + nc);
      const float4 bvg = *(const float4*)(b2 + 256 + nc);
      float a0 = aA[i][j][0] + bva.x, a1 = aA[i][j][1] + bva.y;
      float a2 = aA[i][j][2] + bva.z, a3 = aA[i][j][3] + bva.w;
      float g0 = aG[i][j][0] + bvg.x, g1 = aG[i][j][1] + bvg.y;
      float g2 = aG[i][j][2] + bvg.z, g3 = aG[i][j][3] + bvg.w;
      ushort4 st;
      st.x = f2bf(a0 / (1.0f + __expf(-g0)));
      st.y = f2bf(a1 / (1.0f + __expf(-g1)));
      st.z = f2bf(a2 / (1.0f + __expf(-g2)));
      st.w = f2bf(a3 / (1.0f + __expf(-g3)));
      *(ushort4*)(gout + (size_t)m * 256 + nc) = st;
    }
  }
}

// ---------- fused attention v3: V staged from pre-transposed vT ----------
// NOTE: NO min-waves launch-bounds arg — (256,4) capped VGPR at 64 and spilled.
__global__ __launch_bounds__(256) void attn_kernel(const unsigned short* __restrict__ qkv,
                                                   const unsigned short* __restrict__ vT,
                                                   const float* __restrict__ cbias,
                                                   unsigned short* __restrict__ attnb) {
  __shared__ unsigned short Kl[256 * 32];  // [s][d], 16B-unit swizzled
  __shared__ unsigned short Vl[1024 * 8];  // swizzled image, copied linearly from vT
  const int bh = blockIdx.x, b = bh >> 3, h = bh & 7;
  const int tid = threadIdx.x, lane = tid & 63, w = tid >> 6;
  const int g = lane >> 4, lr = lane & 15;
  const unsigned short* qb_ = qkv + (size_t)b * 196608;
  const unsigned short* vTb = vT + (size_t)bh * 8192;
#pragma unroll
  for (int r = 0; r < 4; ++r) {
    int u = r * 256 + tid;
    int s = u >> 2, sl = u & 3;
    int c = sl ^ ((s >> 1) & 3);
    __builtin_amdgcn_global_load_lds(GAS(qb_ + (size_t)s * 768 + 256 + h * 32 + c * 8),
                                     LAS(&Kl[u * 8]), 16, 0, 0);
    __builtin_amdgcn_global_load_lds(GAS(vTb + u * 8), LAS(&Vl[u * 8]), 16, 0, 0);
  }
  asm volatile("s_waitcnt vmcnt(0)" ::: "memory");
  __syncthreads();
  const float scale = 0.17677669529663689f;
  const fx4 zero = {0.f, 0.f, 0.f, 0.f};
#pragma unroll 1
  for (int it = 0; it < 4; ++it) {
    const int t = it * 64 + w * 16 + lr;
    bx8 qf = *(const bx8*)(qb_ + (size_t)t * 768 + h * 32 + g * 8);
    float p[16][4];
    float mx = -1e30f;
#pragma unroll
    for (int n = 0; n < 16; ++n) {
      int sr = n * 16 + lr;
      bx8 kf = *(const bx8*)&Kl[sr * 32 + (g ^ ((sr >> 1) & 3)) * 8];
      fx4 sc = __builtin_amdgcn_mfma_f32_16x16x32_bf16(kf, qf, zero, 0, 0, 0);
      const float4 cb = *(const float4*)(cbias + (size_t)t * 256 + n * 16 + g * 4);
      p[n][0] = sc[0] * scale + cb.x;
      p[n][1] = sc[1] * scale + cb.y;
      p[n][2] = sc[2] * scale + cb.z;
      p[n][3] = sc[3] * scale + cb.w;
      mx = fmaxf(mx, fmaxf(fmaxf(p[n][0], p[n][1]), fmaxf(p[n][2], p[n][3])));
    }
    mx = fmaxf(mx, __shfl_xor(mx, 16));
    mx = fmaxf(mx, __shfl_xor(mx, 32));
    float sum = 0.f;
    bx8 bq[8];
#pragma unroll
    for (int c = 0; c < 8; ++c) {
      union { bx8 v; unsigned short u[8]; } pk;
#pragma unroll
      for (int jj = 0; jj < 8; ++jj) {
        float e = __expf(p[2 * c + (jj >> 2)][jj & 3] - mx);
        sum += e;
        pk.u[jj] = f2bf(e);
      }
      bq[c] = pk.v;
    }
    sum += __shfl_xor(sum, 16);
    sum += __shfl_xor(sum, 32);
    const float inv = 1.0f / sum;
    fx4 oa0 = zero, oa1 = zero;
#pragma unroll
    for (int c = 0; c < 8; ++c) {
      int u0 = c * 128 + g * 32 + lr;
      int u0p = (u0 & ~7) | ((u0 & 7) ^ ((u0 >> 3) & 7));
      bx8 vf0 = *(const bx8*)&Vl[u0p * 8];
      oa0 = __builtin_amdgcn_mfma_f32_16x16x32_bf16(vf0, bq[c], oa0, 0, 0, 0);
      int u1 = u0 + 16;
      int u1p = (u1 & ~7) | ((u1 & 7) ^ ((u1 >> 3) & 7));
      bx8 vf1 = *(const bx8*)&Vl[u1p * 8];
      oa1 = __builtin_amdgcn_mfma_f32_16x16x32_bf16(vf1, bq[c], oa1, 0, 0, 0);
    }
    ushort4 o0, o1;
    o0.x = f2bf(oa0[0] * inv); o0.y = f2bf(oa0[1] * inv);
    o0.z = f2bf(oa0[2] * inv); o0.w = f2bf(oa0[3] * inv);
    o1.x = f2bf(oa1[0] * inv); o1.y = f2bf(oa1[1] * inv);
    o1.z = f2bf(oa1[2] * inv); o1.w = f2bf(oa1[3] * inv);
    unsigned short* orow = attnb + (size_t)(b * 256 + t) * 256 + h * 32;
    *(ushort4*)(orow + 4 * g) = o0;
    *(ushort4*)(orow + 16 + 4 * g) = o1;
  }
}

// ---------- orchestration ----------
extern "C" void kernel_launch(void* const* d_in, const int* in_sizes, int n_in,
                              void* d_out, int out_size, void* d_ws, size_t ws_size,
                              hipStream_t stream) {
  (void)in_sizes; (void)n_in; (void)out_size; (void)ws_size;
  const float* x     = (const float*)d_in[0];
  const float* cemb  = (const float*)d_in[1];
  const float* pemb  = (const float*)d_in[2];
  const float* cbias = (const float*)d_in[3];
  const float* ln1g  = (const float*)d_in[4];
  const float* ln1b  = (const float*)d_in[5];
  const float* qkvw  = (const float*)d_in[6];
  const float* qkvb  = (const float*)d_in[7];
  const float* outw  = (const float*)d_in[8];
  const float* outbv = (const float*)d_in[9];
  const float* ln2g  = (const float*)d_in[10];
  const float* ln2b  = (const float*)d_in[11];
  const float* w1    = (const float*)d_in[12];
  const float* b1    = (const float*)d_in[13];
  const float* w2    = (const float*)d_in[14];
  const float* b2    = (const float*)d_in[15];
  const float* w3    = (const float*)d_in[16];
  const float* b3    = (const float*)d_in[17];
  const float* fing  = (const float*)d_in[18];
  const float* finb  = (const float*)d_in[19];

  char* ws = (char*)d_ws;
  // Workspace layout (125.0 MB), bytes:
  //  R0 x_res fp32            [0,          33554432)
  //  R1 hn bf16 multiplex     [33554432,   50331648)  ln1-out -> attnb -> ln2-out -> g(W2f out)
  //  R2 big bf16              [50331648,  117440512)
  //     attn phase: qkv [50331648,100663296) + vT [100663296,117440512)
  //     MLP phase : u   [50331648,117440512)  (64 MB, overwrites qkv+vT)
  //  R3 wT bf16               [117440512, 130809856)
  //  R4 stats float2          [130809856, 131072000)
  float* x_res = (float*)(ws);
  unsigned short* hn   = (unsigned short*)(ws + 33554432);
  unsigned short* big  = (unsigned short*)(ws + 50331648);
  unsigned short* vT   = (unsigned short*)(ws + 100663296);
  unsigned short* wT   = (unsigned short*)(ws + 117440512);
  float2* stats = (float2*)(ws + 130809856);
  float* part  = (float*)big;  // mean partials: big dead by then

  unsigned short* qkvwT = wT;                 // 6*768*256
  unsigned short* outwT = wT + 1179648;       // 6*256*256
  unsigned short* w1T   = wT + 1572864;       // 6*1024*256
  unsigned short* w2T   = wT + 3145728;       // 6*512*1024
  unsigned short* w3T   = wT + 6291456;       // 6*256*256

  wtrans_kernel<<<dim3(12, 4, 6), 256, 0, stream>>>(qkvw, qkvwT, 256, 768);
  wtrans_kernel<<<dim3(4, 4, 6), 256, 0, stream>>>(outw, outwT, 256, 256);
  wtrans_kernel<<<dim3(16, 4, 6), 256, 0, stream>>>(w1, w1T, 256, 1024);
  wtrans_kernel<<<dim3(8, 16, 6), 256, 0, stream>>>(w2, w2T, 1024, 512);
  wtrans_kernel<<<dim3(4, 4, 6), 256, 0, stream>>>(w3, w3T, 256, 256);
  embed_kernel<<<8192, 256, 0, stream>>>((const float4*)x, (const float4*)cemb,
                                         (const float4*)pemb, (float4*)x_res);
  for (int l = 0; l < 6; ++l) {
    ln_kernel<0><<<8192, 256, 0, stream>>>(x_res, ln1g + l * 256, ln1b + l * 256, hn, nullptr);
    gemm_kernel<4><<<dim3(6, 256), 256, 0, stream>>>(hn, qkvwT + (size_t)l * 196608,
                                                     qkvb + l * 768, nullptr, (float*)vT,
                                                     big, 768, 256);
    attn_kernel<<<1024, 256, 0, stream>>>(big, vT, cbias, hn);
    gemm64_kernel<2><<<dim3(2, 512), 256, 0, stream>>>(hn, outwT + (size_t)l * 65536,
                                                       outbv + l * 256, cbias, x_res,
                                                       256, 256);
    ln_kernel<0><<<8192, 256, 0, stream>>>(x_res, ln2g + l * 256, ln2b + l * 256, hn, nullptr);
    // MLP, unchunked: u = gelu(hn@W1+b1) [32768x1024] into big (qkv+vT dead)
    gemm_kernel<1><<<dim3(8, 256), 256, 0, stream>>>(hn, w1T + (size_t)l * 262144,
                                                     b1 + l * 1024, nullptr, nullptr, big,
                                                     1024, 256);
    // g = (u@W2a+b2a)*sigmoid(u@W2g+b2g) -> hn (ln2-out dead after W1)
    gemm_w2f64_kernel<<<dim3(2, 512), 256, 0, stream>>>(big, w2T + (size_t)l * 524288,
                                                        b2 + l * 512, hn);
    gemm64_kernel<3><<<dim3(2, 512), 256, 0, stream>>>(hn, w3T + (size_t)l * 65536,
                                                       b3 + l * 256, nullptr, x_res,
                                                       256, 256);
  }
  ln_kernel<1><<<8192, 256, 0, stream>>>(x_res, nullptr, nullptr, nullptr, stats);
  mean_part_kernel<<<dim3(128, 2), 256, 0, stream>>>(x_res, stats, part);
  mean_fin_kernel<<<128, 256, 0, stream>>>(part, fing, finb, (float*)d_out);
}

// Round 9
// 1540.238 us; speedup vs baseline: 1.1334x; 1.0202x over previous
//
#include <hip/hip_runtime.h>

// ---------- types / helpers ----------
typedef __bf16 bx8 __attribute__((ext_vector_type(8)));
typedef float fx4 __attribute__((ext_vector_type(4)));

#define GAS(p) ((const __attribute__((address_space(1))) void*)(const void*)(p))
#define LAS(p) ((__attribute__((address_space(3))) void*)(void*)(p))
// Counted-vmcnt pipeline waits (T4). sched_barrier(0) after each inline-asm
// wait per rule #18 (hipcc may hoist reg-only MFMA past asm waitcnts).
#define WAITVM(n) do { asm volatile("s_waitcnt vmcnt(" #n ")" ::: "memory"); \
                       __builtin_amdgcn_sched_barrier(0); } while (0)
#define WAITLG0() do { asm volatile("s_waitcnt lgkmcnt(0)" ::: "memory"); \
                       __builtin_amdgcn_sched_barrier(0); } while (0)

__device__ __forceinline__ unsigned short f2bf(float f) {
  return __builtin_bit_cast(unsigned short, (__bf16)f);  // native RTNE
}
__device__ __forceinline__ float bf2f(unsigned short s) {
  unsigned u = ((unsigned)s) << 16;
  return __builtin_bit_cast(float, u);
}

// ---------- tiled weight transpose + bf16 cast: dst[l][n][k] = (bf16)src[l][k][n] ----------
__global__ __launch_bounds__(256) void wtrans_kernel(const float* __restrict__ src,
                                                     unsigned short* __restrict__ dst,
                                                     int K, int N) {
  __shared__ unsigned short t[64][68];
  const int l = blockIdx.z;
  const float* s = src + (size_t)l * K * N;
  unsigned short* d = dst + (size_t)l * N * K;
  const int n0 = blockIdx.x * 64, k0 = blockIdx.y * 64;
  const int tx = threadIdx.x & 63, ty = threadIdx.x >> 6;
#pragma unroll
  for (int r = 0; r < 64; r += 4)
    t[tx][ty + r] = f2bf(s[(size_t)(k0 + ty + r) * N + n0 + tx]);
  __syncthreads();
#pragma unroll
  for (int r = 0; r < 64; r += 4)
    d[(size_t)(n0 + ty + r) * K + k0 + tx] = t[ty + r][tx];
}

// ---------- embed: x + col_emb[t] + pos_emb[t+1] ----------
__global__ __launch_bounds__(256) void embed_kernel(const float4* __restrict__ x,
                                                    const float4* __restrict__ ce,
                                                    const float4* __restrict__ pe,
                                                    float4* __restrict__ o) {
  int i = blockIdx.x * 256 + threadIdx.x;
  int c4 = i & 63;
  int t = (i >> 6) & 255;
  float4 a = x[i], b = ce[t * 64 + c4], p = pe[(t + 1) * 64 + c4];
  o[i] = make_float4(a.x + b.x + p.x, a.y + b.y + p.y, a.z + b.z + p.z, a.w + b.w + p.w);
}

// ---------- LayerNorm ----------
template <int MODE>
__global__ __launch_bounds__(256) void ln_kernel(const float* __restrict__ x,
                                                 const float* __restrict__ gw,
                                                 const float* __restrict__ bw,
                                                 unsigned short* __restrict__ out,
                                                 float2* __restrict__ stats) {
  int row = blockIdx.x * 4 + (threadIdx.x >> 6);
  int lane = threadIdx.x & 63;
  const float4 v = *(const float4*)(x + (size_t)row * 256 + lane * 4);
  float s = v.x + v.y + v.z + v.w;
  float q = v.x * v.x + v.y * v.y + v.z * v.z + v.w * v.w;
#pragma unroll
  for (int off = 1; off < 64; off <<= 1) {
    s += __shfl_xor(s, off);
    q += __shfl_xor(q, off);
  }
  float mean = s * (1.0f / 256.0f);
  float rs = rsqrtf(q * (1.0f / 256.0f) - mean * mean + 1e-5f);
  if (MODE == 1) {
    if (lane == 0) stats[row] = make_float2(mean, rs);
    return;
  }
  float4 gv = *(const float4*)(gw + lane * 4);
  float4 bv = *(const float4*)(bw + lane * 4);
  ushort4 o;
  o.x = f2bf((v.x - mean) * rs * gv.x + bv.x);
  o.y = f2bf((v.y - mean) * rs * gv.y + bv.y);
  o.z = f2bf((v.z - mean) * rs * gv.z + bv.z);
  o.w = f2bf((v.w - mean) * rs * gv.w + bv.w);
  *(ushort4*)(out + (size_t)row * 256 + lane * 4) = o;
}

// ---------- final mean, two-stage ----------
__global__ __launch_bounds__(256) void mean_part_kernel(const float* __restrict__ x,
                                                        const float2* __restrict__ stats,
                                                        float* __restrict__ part) {
  int b = blockIdx.x, half = blockIdx.y, c = threadIdx.x;
  const float* xb = x + (size_t)b * 65536 + half * 32768;
  const float2* st = stats + b * 256 + half * 128;
  float acc = 0.f;
#pragma unroll 4
  for (int t = 0; t < 128; ++t) {
    float2 s = st[t];
    acc += (xb[t * 256 + c] - s.x) * s.y;
  }
  part[(size_t)(b * 2 + half) * 256 + c] = acc;
}
__global__ __launch_bounds__(256) void mean_fin_kernel(const float* __restrict__ part,
                                                       const float* __restrict__ fg,
                                                       const float* __restrict__ fb,
                                                       float* __restrict__ out) {
  int b = blockIdx.x, c = threadIdx.x;
  out[b * 256 + c] =
      (part[(size_t)(2 * b) * 256 + c] + part[(size_t)(2 * b + 1) * 256 + c]) *
          (1.0f / 256.0f) * fg[c] + fb[c];
}

// ---------- GEMM 128x128, counted-vmcnt pipeline (4 loads/stage) ----------
// acc[i][j] = mfma(bq[j], af[i], ·): lane (g,lr) reg r holds
//   C[m0+wr*64+i*16+lr][n0+wc*64+j*16+4g+r]
// EP 1: out_bf16 = gelu_exact(acc + bvec)
// EP 4: qkv: cols<512 -> outb; cols>=512 (V) -> vT in attn-Vl swizzled image
// Race safety: barrier#1 after vmcnt(L) -> buf[t&1] fully staged for all waves;
// barrier#2 after lgkmcnt(0) -> all waves hold frags in regs, buf reusable.
template <int EP>
__global__ __launch_bounds__(256) void gemm_kernel(const unsigned short* __restrict__ A,
                                                   const unsigned short* __restrict__ BT,
                                                   const float* __restrict__ bvec,
                                                   const float* __restrict__ cbias,
                                                   float* __restrict__ resid,
                                                   unsigned short* __restrict__ outb,
                                                   int N, int K) {
  __shared__ unsigned short lA[2][128 * 32];
  __shared__ unsigned short lB[2][128 * 32];
  const int tid = threadIdx.x;
  const int lane = tid & 63, w = tid >> 6;
  const int wr = w >> 1, wc = w & 1;
  const int g = lane >> 4, lr = lane & 15;
  const int m0 = blockIdx.y * 128, n0 = blockIdx.x * 128;
  fx4 acc[4][4] = {};

  auto STAGE = [&](int buf, int kk) {
#pragma unroll
    for (int r = 0; r < 2; ++r) {
      int u = r * 256 + tid;
      int row = u >> 2, sl = u & 3;
      int c = sl ^ ((row >> 1) & 3);
      __builtin_amdgcn_global_load_lds(GAS(A + (size_t)(m0 + row) * K + kk + c * 8),
                                       LAS(&lA[buf][u * 8]), 16, 0, 0);
      __builtin_amdgcn_global_load_lds(GAS(BT + (size_t)(n0 + row) * K + kk + c * 8),
                                       LAS(&lB[buf][u * 8]), 16, 0, 0);
    }
  };

  const int nt = K >> 5;
  STAGE(0, 0);
  STAGE(1, 32);
  for (int t = 0; t < nt; ++t) {
    if (t == nt - 1) WAITVM(0); else WAITVM(4);
    __builtin_amdgcn_s_barrier();
    const int buf = t & 1;
    bx8 af[4], bq[4];
#pragma unroll
    for (int i = 0; i < 4; ++i) {
      int row = wr * 64 + i * 16 + lr;
      af[i] = *(const bx8*)&lA[buf][row * 32 + (g ^ ((row >> 1) & 3)) * 8];
      int col = wc * 64 + i * 16 + lr;
      bq[i] = *(const bx8*)&lB[buf][col * 32 + (g ^ ((col >> 1) & 3)) * 8];
    }
    WAITLG0();
    __builtin_amdgcn_s_barrier();
    if (t + 2 < nt) STAGE(buf, (t + 2) * 32);
#pragma unroll
    for (int i = 0; i < 4; ++i)
#pragma unroll
      for (int j = 0; j < 4; ++j)
        acc[i][j] = __builtin_amdgcn_mfma_f32_16x16x32_bf16(bq[j], af[i], acc[i][j], 0, 0, 0);
  }

#pragma unroll
  for (int i = 0; i < 4; ++i) {
    const int m = m0 + wr * 64 + i * 16 + lr;
#pragma unroll
    for (int j = 0; j < 4; ++j) {
      const int nc = n0 + wc * 64 + j * 16 + g * 4;
      const float4 bv = *(const float4*)(bvec + nc);
      float v0 = acc[i][j][0] + bv.x, v1 = acc[i][j][1] + bv.y;
      float v2 = acc[i][j][2] + bv.z, v3 = acc[i][j][3] + bv.w;
      if constexpr (EP == 1) {
        v0 = 0.5f * v0 * (1.0f + erff(v0 * 0.70710678118654752f));
        v1 = 0.5f * v1 * (1.0f + erff(v1 * 0.70710678118654752f));
        v2 = 0.5f * v2 * (1.0f + erff(v2 * 0.70710678118654752f));
        v3 = 0.5f * v3 * (1.0f + erff(v3 * 0.70710678118654752f));
      }
      if constexpr (EP == 0 || EP == 1) {
        ushort4 st;
        st.x = f2bf(v0); st.y = f2bf(v1); st.z = f2bf(v2); st.w = f2bf(v3);
        *(ushort4*)(outb + (size_t)m * N + nc) = st;
      } else {  // EP 4
        if (nc < 512) {
          ushort4 st;
          st.x = f2bf(v0); st.y = f2bf(v1); st.z = f2bf(v2); st.w = f2bf(v3);
          *(ushort4*)(outb + (size_t)m * N + nc) = st;
        } else {
          unsigned short* vTp = (unsigned short*)resid;
          const int s = m & 255, b = m >> 8;
          const int hv = nc - 512;
          const int h = hv >> 5, d0 = hv & 31;
          const int jj = (s & 3) + 4 * ((s >> 4) & 1);
          const int ub = (s >> 5) * 128 + ((s >> 2) & 3) * 32 + d0;
          unsigned short* base = vTp + (size_t)(b * 8 + h) * 8192;
          const float vv[4] = {v0, v1, v2, v3};
#pragma unroll
          for (int r = 0; r < 4; ++r) {
            int u = ub + r;
            int up = (u & ~7) | ((u & 7) ^ ((u >> 3) & 7));
            base[up * 8 + jj] = f2bf(vv[r]);
          }
        }
      }
    }
  }
}

// ---------- GEMM 64x128 (BM=64), counted-vmcnt pipeline (3 loads/stage) ----------
// EP 2: resid += acc + bvec + col_bias[s][n]  (float4 RMW)
// EP 3: resid += acc + bvec                   (float4 RMW)
template <int EP>
__global__ __launch_bounds__(256) void gemm64_kernel(const unsigned short* __restrict__ A,
                                                     const unsigned short* __restrict__ BT,
                                                     const float* __restrict__ bvec,
                                                     const float* __restrict__ cbias,
                                                     float* __restrict__ resid,
                                                     int N, int K) {
  __shared__ unsigned short lA[2][64 * 32];
  __shared__ unsigned short lB[2][128 * 32];
  const int tid = threadIdx.x;
  const int lane = tid & 63, w = tid >> 6;
  const int g = lane >> 4, lr = lane & 15;
  const int m0 = blockIdx.y * 64, n0 = blockIdx.x * 128;
  fx4 acc[4][2] = {};

  auto STAGE = [&](int buf, int kk) {
    {
      int u = tid;
      int row = u >> 2, sl = u & 3;
      int c = sl ^ ((row >> 1) & 3);
      __builtin_amdgcn_global_load_lds(GAS(A + (size_t)(m0 + row) * K + kk + c * 8),
                                       LAS(&lA[buf][u * 8]), 16, 0, 0);
    }
#pragma unroll
    for (int r = 0; r < 2; ++r) {
      int u = r * 256 + tid;
      int row = u >> 2, sl = u & 3;
      int c = sl ^ ((row >> 1) & 3);
      __builtin_amdgcn_global_load_lds(GAS(BT + (size_t)(n0 + row) * K + kk + c * 8),
                                       LAS(&lB[buf][u * 8]), 16, 0, 0);
    }
  };

  const int nt = K >> 5;
  STAGE(0, 0);
  STAGE(1, 32);
  for (int t = 0; t < nt; ++t) {
    if (t == nt - 1) WAITVM(0); else WAITVM(3);
    __builtin_amdgcn_s_barrier();
    const int buf = t & 1;
    bx8 af[4], bq[2];
#pragma unroll
    for (int i = 0; i < 4; ++i) {
      int row = i * 16 + lr;
      af[i] = *(const bx8*)&lA[buf][row * 32 + (g ^ ((row >> 1) & 3)) * 8];
    }
#pragma unroll
    for (int j = 0; j < 2; ++j) {
      int col = w * 32 + j * 16 + lr;
      bq[j] = *(const bx8*)&lB[buf][col * 32 + (g ^ ((col >> 1) & 3)) * 8];
    }
    WAITLG0();
    __builtin_amdgcn_s_barrier();
    if (t + 2 < nt) STAGE(buf, (t + 2) * 32);
#pragma unroll
    for (int i = 0; i < 4; ++i)
#pragma unroll
      for (int j = 0; j < 2; ++j)
        acc[i][j] = __builtin_amdgcn_mfma_f32_16x16x32_bf16(bq[j], af[i], acc[i][j], 0, 0, 0);
  }

#pragma unroll
  for (int i = 0; i < 4; ++i) {
    const int m = m0 + i * 16 + lr;
#pragma unroll
    for (int j = 0; j < 2; ++j) {
      const int nc = n0 + w * 32 + j * 16 + g * 4;
      const float4 bv = *(const float4*)(bvec + nc);
      float v0 = acc[i][j][0] + bv.x, v1 = acc[i][j][1] + bv.y;
      float v2 = acc[i][j][2] + bv.z, v3 = acc[i][j][3] + bv.w;
      if constexpr (EP == 2) {
        const float4 cb = *(const float4*)(cbias + (size_t)(m & 255) * 256 + nc);
        v0 += cb.x; v1 += cb.y; v2 += cb.z; v3 += cb.w;
      }
      float4* rp = (float4*)(resid + (size_t)m * N + nc);
      float4 old = *rp;
      *rp = make_float4(old.x + v0, old.y + v1, old.z + v2, old.w + v3);
    }
  }
}

// ---------- fused W2+swiglu BM=64, counted-vmcnt pipeline (5 loads/stage) ----------
__global__ __launch_bounds__(256) void gemm_w2f64_kernel(const unsigned short* __restrict__ A,
                                                         const unsigned short* __restrict__ BT,
                                                         const float* __restrict__ b2,
                                                         unsigned short* __restrict__ gout) {
  __shared__ unsigned short lA[2][64 * 32];
  __shared__ unsigned short lBa[2][128 * 32];
  __shared__ unsigned short lBg[2][128 * 32];
  const int tid = threadIdx.x;
  const int lane = tid & 63, w = tid >> 6;
  const int g = lane >> 4, lr = lane & 15;
  const int m0 = blockIdx.y * 64, n0 = blockIdx.x * 128;
  fx4 aA[4][2] = {}, aG[4][2] = {};

  auto STAGE = [&](int buf, int kk) {
    {
      int u = tid;
      int row = u >> 2, sl = u & 3;
      int c = sl ^ ((row >> 1) & 3);
      __builtin_amdgcn_global_load_lds(GAS(A + (size_t)(m0 + row) * 1024 + kk + c * 8),
                                       LAS(&lA[buf][u * 8]), 16, 0, 0);
    }
#pragma unroll
    for (int r = 0; r < 2; ++r) {
      int u = r * 256 + tid;
      int row = u >> 2, sl = u & 3;
      int c = sl ^ ((row >> 1) & 3);
      __builtin_amdgcn_global_load_lds(GAS(BT + (size_t)(n0 + row) * 1024 + kk + c * 8),
                                       LAS(&lBa[buf][u * 8]), 16, 0, 0);
      __builtin_amdgcn_global_load_lds(GAS(BT + (size_t)(256 + n0 + row) * 1024 + kk + c * 8),
                                       LAS(&lBg[buf][u * 8]), 16, 0, 0);
    }
  };

  STAGE(0, 0);
  STAGE(1, 32);
  for (int t = 0; t < 32; ++t) {
    if (t == 31) WAITVM(0); else WAITVM(5);
    __builtin_amdgcn_s_barrier();
    const int buf = t & 1;
    bx8 af[4], ba[2], bg[2];
#pragma unroll
    for (int i = 0; i < 4; ++i) {
      int row = i * 16 + lr;
      af[i] = *(const bx8*)&lA[buf][row * 32 + (g ^ ((row >> 1) & 3)) * 8];
    }
#pragma unroll
    for (int j = 0; j < 2; ++j) {
      int col = w * 32 + j * 16 + lr;
      int sw = (g ^ ((col >> 1) & 3)) * 8;
      ba[j] = *(const bx8*)&lBa[buf][col * 32 + sw];
      bg[j] = *(const bx8*)&lBg[buf][col * 32 + sw];
    }
    WAITLG0();
    __builtin_amdgcn_s_barrier();
    if (t + 2 < 32) STAGE(buf, (t + 2) * 32);
#pragma unroll
    for (int i = 0; i < 4; ++i)
#pragma unroll
      for (int j = 0; j < 2; ++j) {
        aA[i][j] = __builtin_amdgcn_mfma_f32_16x16x32_bf16(ba[j], af[i], aA[i][j], 0, 0, 0);
        aG[i][j] = __builtin_amdgcn_mfma_f32_16x16x32_bf16(bg[j], af[i], aG[i][j], 0, 0, 0);
      }
  }

#pragma unroll
  for (int i = 0; i < 4; ++i) {
    const int m = m0 + i * 16 + lr;
#pragma unroll
    for (int j = 0; j < 2; ++j) {
      const int nc = n0 + w * 32 + j * 16 + g * 4;
      const float4 bva = *(const float4*)(b2 + nc);
      const float4 bvg = *(const float4*)(b2 + 256 + nc);
      float a0 = aA[i][j][0] + bva.x, a1 = aA[i][j][1] + bva.y;
      float a2 = aA[i][j][2] + bva.z, a3 = aA[i][j][3] + bva.w;
      float g0 = aG[i][j][0] + bvg.x, g1 = aG[i][j][1] + bvg.y;
      float g2 = aG[i][j][2] + bvg.z, g3 = aG[i][j][3] + bvg.w;
      ushort4 st;
      st.x = f2bf(a0 / (1.0f + __expf(-g0)));
      st.y = f2bf(a1 / (1.0f + __expf(-g1)));
      st.z = f2bf(a2 / (1.0f + __expf(-g2)));
      st.w = f2bf(a3 / (1.0f + __expf(-g3)));
      *(ushort4*)(gout + (size_t)m * 256 + nc) = st;
    }
  }
}

// ---------- fused attention v3: V staged from pre-transposed vT ----------
// NOTE: NO min-waves launch-bounds arg — (256,4) capped VGPR at 64 and spilled.
__global__ __launch_bounds__(256) void attn_kernel(const unsigned short* __restrict__ qkv,
                                                   const unsigned short* __restrict__ vT,
                                                   const float* __restrict__ cbias,
                                                   unsigned short* __restrict__ attnb) {
  __shared__ unsigned short Kl[256 * 32];  // [s][d], 16B-unit swizzled
  __shared__ unsigned short Vl[1024 * 8];  // swizzled image, copied linearly from vT
  const int bh = blockIdx.x, b = bh >> 3, h = bh & 7;
  const int tid = threadIdx.x, lane = tid & 63, w = tid >> 6;
  const int g = lane >> 4, lr = lane & 15;
  const unsigned short* qb_ = qkv + (size_t)b * 196608;
  const unsigned short* vTb = vT + (size_t)bh * 8192;
#pragma unroll
  for (int r = 0; r < 4; ++r) {
    int u = r * 256 + tid;
    int s = u >> 2, sl = u & 3;
    int c = sl ^ ((s >> 1) & 3);
    __builtin_amdgcn_global_load_lds(GAS(qb_ + (size_t)s * 768 + 256 + h * 32 + c * 8),
                                     LAS(&Kl[u * 8]), 16, 0, 0);
    __builtin_amdgcn_global_load_lds(GAS(vTb + u * 8), LAS(&Vl[u * 8]), 16, 0, 0);
  }
  asm volatile("s_waitcnt vmcnt(0)" ::: "memory");
  __syncthreads();
  const float scale = 0.17677669529663689f;
  const fx4 zero = {0.f, 0.f, 0.f, 0.f};
#pragma unroll 1
  for (int it = 0; it < 4; ++it) {
    const int t = it * 64 + w * 16 + lr;
    bx8 qf = *(const bx8*)(qb_ + (size_t)t * 768 + h * 32 + g * 8);
    float p[16][4];
    float mx = -1e30f;
#pragma unroll
    for (int n = 0; n < 16; ++n) {
      int sr = n * 16 + lr;
      bx8 kf = *(const bx8*)&Kl[sr * 32 + (g ^ ((sr >> 1) & 3)) * 8];
      fx4 sc = __builtin_amdgcn_mfma_f32_16x16x32_bf16(kf, qf, zero, 0, 0, 0);
      const float4 cb = *(const float4*)(cbias + (size_t)t * 256 + n * 16 + g * 4);
      p[n][0] = sc[0] * scale + cb.x;
      p[n][1] = sc[1] * scale + cb.y;
      p[n][2] = sc[2] * scale + cb.z;
      p[n][3] = sc[3] * scale + cb.w;
      mx = fmaxf(mx, fmaxf(fmaxf(p[n][0], p[n][1]), fmaxf(p[n][2], p[n][3])));
    }
    mx = fmaxf(mx, __shfl_xor(mx, 16));
    mx = fmaxf(mx, __shfl_xor(mx, 32));
    float sum = 0.f;
    bx8 bq[8];
#pragma unroll
    for (int c = 0; c < 8; ++c) {
      union { bx8 v; unsigned short u[8]; } pk;
#pragma unroll
      for (int jj = 0; jj < 8; ++jj) {
        float e = __expf(p[2 * c + (jj >> 2)][jj & 3] - mx);
        sum += e;
        pk.u[jj] = f2bf(e);
      }
      bq[c] = pk.v;
    }
    sum += __shfl_xor(sum, 16);
    sum += __shfl_xor(sum, 32);
    const float inv = 1.0f / sum;
    fx4 oa0 = zero, oa1 = zero;
#pragma unroll
    for (int c = 0; c < 8; ++c) {
      int u0 = c * 128 + g * 32 + lr;
      int u0p = (u0 & ~7) | ((u0 & 7) ^ ((u0 >> 3) & 7));
      bx8 vf0 = *(const bx8*)&Vl[u0p * 8];
      oa0 = __builtin_amdgcn_mfma_f32_16x16x32_bf16(vf0, bq[c], oa0, 0, 0, 0);
      int u1 = u0 + 16;
      int u1p = (u1 & ~7) | ((u1 & 7) ^ ((u1 >> 3) & 7));
      bx8 vf1 = *(const bx8*)&Vl[u1p * 8];
      oa1 = __builtin_amdgcn_mfma_f32_16x16x32_bf16(vf1, bq[c], oa1, 0, 0, 0);
    }
    ushort4 o0, o1;
    o0.x = f2bf(oa0[0] * inv); o0.y = f2bf(oa0[1] * inv);
    o0.z = f2bf(oa0[2] * inv); o0.w = f2bf(oa0[3] * inv);
    o1.x = f2bf(oa1[0] * inv); o1.y = f2bf(oa1[1] * inv);
    o1.z = f2bf(oa1[2] * inv); o1.w = f2bf(oa1[3] * inv);
    unsigned short* orow = attnb + (size_t)(b * 256 + t) * 256 + h * 32;
    *(ushort4*)(orow + 4 * g) = o0;
    *(ushort4*)(orow + 16 + 4 * g) = o1;
  }
}

// ---------- orchestration ----------
extern "C" void kernel_launch(void* const* d_in, const int* in_sizes, int n_in,
                              void* d_out, int out_size, void* d_ws, size_t ws_size,
                              hipStream_t stream) {
  (void)in_sizes; (void)n_in; (void)out_size; (void)ws_size;
  const float* x     = (const float*)d_in[0];
  const float* cemb  = (const float*)d_in[1];
  const float* pemb  = (const float*)d_in[2];
  const float* cbias = (const float*)d_in[3];
  const float* ln1g  = (const float*)d_in[4];
  const float* ln1b  = (const float*)d_in[5];
  const float* qkvw  = (const float*)d_in[6];
  const float* qkvb  = (const float*)d_in[7];
  const float* outw  = (const float*)d_in[8];
  const float* outbv = (const float*)d_in[9];
  const float* ln2g  = (const float*)d_in[10];
  const float* ln2b  = (const float*)d_in[11];
  const float* w1    = (const float*)d_in[12];
  const float* b1    = (const float*)d_in[13];
  const float* w2    = (const float*)d_in[14];
  const float* b2    = (const float*)d_in[15];
  const float* w3    = (const float*)d_in[16];
  const float* b3    = (const float*)d_in[17];
  const float* fing  = (const float*)d_in[18];
  const float* finb  = (const float*)d_in[19];

  char* ws = (char*)d_ws;
  // Workspace layout (125.0 MB), bytes:
  //  R0 x_res fp32            [0,          33554432)
  //  R1 hn bf16 multiplex     [33554432,   50331648)  ln1-out -> attnb -> ln2-out -> g(W2f out)
  //  R2 big bf16              [50331648,  117440512)
  //     attn phase: qkv [50331648,100663296) + vT [100663296,117440512)
  //     MLP phase : u   [50331648,117440512)  (64 MB, overwrites qkv+vT)
  //  R3 wT bf16               [117440512, 130809856)
  //  R4 stats float2          [130809856, 131072000)
  float* x_res = (float*)(ws);
  unsigned short* hn   = (unsigned short*)(ws + 33554432);
  unsigned short* big  = (unsigned short*)(ws + 50331648);
  unsigned short* vT   = (unsigned short*)(ws + 100663296);
  unsigned short* wT   = (unsigned short*)(ws + 117440512);
  float2* stats = (float2*)(ws + 130809856);
  float* part  = (float*)big;  // mean partials: big dead by then

  unsigned short* qkvwT = wT;                 // 6*768*256
  unsigned short* outwT = wT + 1179648;       // 6*256*256
  unsigned short* w1T   = wT + 1572864;       // 6*1024*256
  unsigned short* w2T   = wT + 3145728;       // 6*512*1024
  unsigned short* w3T   = wT + 6291456;       // 6*256*256

  wtrans_kernel<<<dim3(12, 4, 6), 256, 0, stream>>>(qkvw, qkvwT, 256, 768);
  wtrans_kernel<<<dim3(4, 4, 6), 256, 0, stream>>>(outw, outwT, 256, 256);
  wtrans_kernel<<<dim3(16, 4, 6), 256, 0, stream>>>(w1, w1T, 256, 1024);
  wtrans_kernel<<<dim3(8, 16, 6), 256, 0, stream>>>(w2, w2T, 1024, 512);
  wtrans_kernel<<<dim3(4, 4, 6), 256, 0, stream>>>(w3, w3T, 256, 256);
  embed_kernel<<<8192, 256, 0, stream>>>((const float4*)x, (const float4*)cemb,
                                         (const float4*)pemb, (float4*)x_res);
  for (int l = 0; l < 6; ++l) {
    ln_kernel<0><<<8192, 256, 0, stream>>>(x_res, ln1g + l * 256, ln1b + l * 256, hn, nullptr);
    gemm_kernel<4><<<dim3(6, 256), 256, 0, stream>>>(hn, qkvwT + (size_t)l * 196608,
                                                     qkvb + l * 768, nullptr, (float*)vT,
                                                     big, 768, 256);
    attn_kernel<<<1024, 256, 0, stream>>>(big, vT, cbias, hn);
    gemm64_kernel<2><<<dim3(2, 512), 256, 0, stream>>>(hn, outwT + (size_t)l * 65536,
                                                       outbv + l * 256, cbias, x_res,
                                                       256, 256);
    ln_kernel<0><<<8192, 256, 0, stream>>>(x_res, ln2g + l * 256, ln2b + l * 256, hn, nullptr);
    gemm_kernel<1><<<dim3(8, 256), 256, 0, stream>>>(hn, w1T + (size_t)l * 262144,
                                                     b1 + l * 1024, nullptr, nullptr, big,
                                                     1024, 256);
    gemm_w2f64_kernel<<<dim3(2, 512), 256, 0, stream>>>(big, w2T + (size_t)l * 524288,
                                                        b2 + l * 512, hn);
    gemm64_kernel<3><<<dim3(2, 512), 256, 0, stream>>>(hn, w3T + (size_t)l * 65536,
                                                       b3 + l * 256, nullptr, x_res,
                                                       256, 256);
  }
  ln_kernel<1><<<8192, 256, 0, stream>>>(x_res, nullptr, nullptr, nullptr, stats);
  mean_part_kernel<<<dim3(128, 2), 256, 0, stream>>>(x_res, stats, part);
  mean_fin_kernel<<<128, 256, 0, stream>>>(part, fing, finb, (float*)d_out);
}